// Round 3
// baseline (390.500 us; speedup 1.0000x reference)
//
#include <hip/hip_runtime.h>
#include <hip/hip_bf16.h>
#include <math.h>

#define N_ROWS 32768
#define H      512
#define GV     640
#define V      320
#define DG     128
#define M_TILE 32
#define K_TILE 64

// Fused: logits GEMM (fp32) + gumbel argmax + softmax marginal accumulation + codevector gather.
// Block: 512 threads (8 waves). Each wave owns 4 rows; each lane owns cols tn + 64*j (j=0..9):
// j=0..4 -> group 0, j=5..9 -> group 1 (uniform per lane).
// 4 rows/wave (acc[4][10]=40 VGPR) instead of 8 -> ~2x resident waves vs round 2 for latency hiding.
__global__ __launch_bounds__(512, 4)
void gumbel_vq_main(const float* __restrict__ hidden,
                    const int*   __restrict__ mask,
                    const float* __restrict__ gumbel,
                    const float* __restrict__ W,
                    const float* __restrict__ bias,
                    const float* __restrict__ codevec,
                    float* __restrict__ out,
                    float* __restrict__ ws)
{
    __shared__ float smem[5120];          // GEMM h-tile: 32*68=2176 floats; reuse as [8][640] reduce buf
    const int tid  = threadIdx.x;
    const int tn   = tid & 63;
    const int tm   = tid >> 6;            // wave id 0..7
    const int row0 = blockIdx.x * M_TILE;

    // accumulators init = bias
    float acc[4][10];
    #pragma unroll
    for (int j = 0; j < 10; ++j) {
        float b = bias[tn + 64 * j];
        #pragma unroll
        for (int r = 0; r < 4; ++r) acc[r][j] = b;
    }

    // hidden staging: 32 rows x 64 k = 2048 floats = 512 threads x 1 float4
    const int lrow = tid >> 4;            // 0..31
    const int lk   = (tid & 15) * 4;      // 0..60
    const float* hsrc = hidden + (size_t)(row0 + lrow) * H + lk;

    float4 nxt = *(const float4*)hsrc;    // prefetch tile 0

    for (int kt = 0; kt < H; kt += K_TILE) {
        __syncthreads();
        *(float4*)&smem[lrow * 68 + lk] = nxt;   // stride 68: pad breaks power-of-2 conflicts
        __syncthreads();
        if (kt + K_TILE < H)
            nxt = *(const float4*)(hsrc + kt + K_TILE);  // prefetch next tile during compute

        #pragma unroll 2
        for (int kk = 0; kk < K_TILE; kk += 4) {
            float4 hv[4];
            #pragma unroll
            for (int r = 0; r < 4; ++r)
                hv[r] = *(const float4*)&smem[(tm * 4 + r) * 68 + kk];   // broadcast across lanes
            #pragma unroll
            for (int q = 0; q < 4; ++q) {
                const float* Wk = W + (size_t)(kt + kk + q) * GV + tn;
                float w[10];
                #pragma unroll
                for (int j = 0; j < 10; ++j) w[j] = Wk[64 * j];          // coalesced per j
                #pragma unroll
                for (int r = 0; r < 4; ++r) {
                    float h = (q == 0) ? hv[r].x : (q == 1) ? hv[r].y : (q == 2) ? hv[r].z : hv[r].w;
                    #pragma unroll
                    for (int j = 0; j < 10; ++j)
                        acc[r][j] = fmaf(h, w[j], acc[r][j]);
                }
            }
        }
    }

    // ---- epilogue: per-row argmax / softmax / gather ----
    float marg[10];
    #pragma unroll
    for (int j = 0; j < 10; ++j) marg[j] = 0.f;

    // MUST be unrolled: runtime-indexed acc[r][...] would force the whole
    // accumulator array to scratch for the entire kernel (rule #20) — that
    // was a 23 GB HBM-write storm and 12x slowdown in round 1.
    #pragma unroll
    for (int r = 0; r < 4; ++r) {
        const int rloc = tm * 4 + r;
        const int row  = row0 + rloc;
        const float mrow = (mask[row] != 0) ? 1.f : 0.f;

        float z[10];
        #pragma unroll
        for (int j = 0; j < 10; ++j)
            z[j] = acc[r][j] + gumbel[(size_t)row * GV + tn + 64 * j];

        // lane-local argmax (logits+gumbel) and max (plain logits) per group
        float zm0 = z[0]; int zi0 = tn;          float lm0 = acc[r][0];
        #pragma unroll
        for (int j = 1; j < 5; ++j) {
            int c = tn + 64 * j;
            if (z[j] > zm0) { zm0 = z[j]; zi0 = c; }
            lm0 = fmaxf(lm0, acc[r][j]);
        }
        float zm1 = z[5]; int zi1 = tn + 320;    float lm1 = acc[r][5];
        #pragma unroll
        for (int j = 6; j < 10; ++j) {
            int c = tn + 64 * j;
            if (z[j] > zm1) { zm1 = z[j]; zi1 = c; }
            lm1 = fmaxf(lm1, acc[r][j]);
        }

        // 64-lane butterfly: argmax with first-index tie-break (matches jnp.argmax), plus plain max
        #pragma unroll
        for (int d = 32; d >= 1; d >>= 1) {
            float oz; int oi;
            oz = __shfl_xor(zm0, d, 64); oi = __shfl_xor(zi0, d, 64);
            if (oz > zm0 || (oz == zm0 && oi < zi0)) { zm0 = oz; zi0 = oi; }
            oz = __shfl_xor(zm1, d, 64); oi = __shfl_xor(zi1, d, 64);
            if (oz > zm1 || (oz == zm1 && oi < zi1)) { zm1 = oz; zi1 = oi; }
            lm0 = fmaxf(lm0, __shfl_xor(lm0, d, 64));
            lm1 = fmaxf(lm1, __shfl_xor(lm1, d, 64));
        }

        // softmax(plain logits) per group -> masked marginal accumulation
        float p[10];
        float s0 = 0.f, s1 = 0.f;
        #pragma unroll
        for (int j = 0; j < 5; ++j)  { p[j] = __expf(acc[r][j] - lm0); s0 += p[j]; }
        #pragma unroll
        for (int j = 5; j < 10; ++j) { p[j] = __expf(acc[r][j] - lm1); s1 += p[j]; }
        #pragma unroll
        for (int d = 32; d >= 1; d >>= 1) {
            s0 += __shfl_xor(s0, d, 64);
            s1 += __shfl_xor(s1, d, 64);
        }
        float inv0 = mrow / s0, inv1 = mrow / s1;
        #pragma unroll
        for (int j = 0; j < 5; ++j)  marg[j] += p[j] * inv0;
        #pragma unroll
        for (int j = 5; j < 10; ++j) marg[j] += p[j] * inv1;

        // codevector gather-write: lanes 0..31 write group 0's 128 floats, lanes 32..63 group 1
        int g   = tn >> 5;
        int idx = g ? (zi1 - V) : zi0;
        const float4* src = (const float4*)(codevec + ((size_t)g * V + idx) * DG);
        float4 vv = src[tn & 31];
        ((float4*)(out + (size_t)row * (2 * DG) + g * DG))[tn & 31] = vv;
    }

    // ---- cross-wave marginal reduce -> global atomics ----
    __syncthreads();                       // protect smem reuse
    #pragma unroll
    for (int j = 0; j < 10; ++j) smem[tm * GV + tn + 64 * j] = marg[j];
    __syncthreads();
    for (int c = tid; c < GV; c += 512) {
        float s = 0.f;
        #pragma unroll
        for (int w = 0; w < 8; ++w) s += smem[w * GV + c];
        atomicAdd(&ws[c], s);
    }

    // mask count: wave 0 ballots its block's 32 rows, one atomic per block
    if (tm == 0) {
        int mr = (tn < M_TILE) ? (mask[row0 + tn] != 0) : 0;
        unsigned long long b = __ballot(mr);
        if (tn == 0) atomicAdd(&ws[GV], (float)__popcll(b));
    }
}

__global__ void gumbel_vq_finalize(const float* __restrict__ ws, float* __restrict__ out)
{
    __shared__ float red[GV];
    int t = threadIdx.x;
    float cnt = ws[GV];
    float p = ws[t] / cnt;
    red[t] = p * logf(p + 1e-7f);
    __syncthreads();
    if (t == 0) {
        float e0 = 0.f, e1 = 0.f;
        for (int i = 0; i < V; ++i)  e0 += red[i];
        for (int i = V; i < GV; ++i) e1 += red[i];
        out[(size_t)N_ROWS * 2 * DG] = expf(-e0) + expf(-e1);
    }
}

extern "C" void kernel_launch(void* const* d_in, const int* in_sizes, int n_in,
                              void* d_out, int out_size, void* d_ws, size_t ws_size,
                              hipStream_t stream)
{
    const float* hidden  = (const float*)d_in[0];
    const int*   mask    = (const int*)  d_in[1];
    const float* gumbel  = (const float*)d_in[2];
    const float* W       = (const float*)d_in[3];
    const float* bias    = (const float*)d_in[4];
    const float* codevec = (const float*)d_in[5];
    float* out = (float*)d_out;
    float* ws  = (float*)d_ws;

    hipMemsetAsync(d_ws, 0, (GV + 1) * sizeof(float), stream);
    gumbel_vq_main<<<N_ROWS / M_TILE, 512, 0, stream>>>(hidden, mask, gumbel, W, bias, codevec, out, ws);
    gumbel_vq_finalize<<<1, GV, 0, stream>>>(ws, out);
}

// Round 4
// 327.733 us; speedup vs baseline: 1.1915x; 1.1915x over previous
//
#include <hip/hip_runtime.h>
#include <hip/hip_bf16.h>
#include <math.h>

#define N_ROWS 32768
#define H      512
#define GV     640
#define V      320
#define DG     128
#define M_TILE 64
#define K_TILE 64

// Fused: logits GEMM (fp32) + gumbel argmax + softmax marginal accumulation + codevector gather.
// Block: 512 threads (8 waves), M_TILE=64 rows: each wave owns 8 rows. Each lane owns cols
// tn + 64*j (j=0..9, coalesced): j=0..4 -> group 0, j=5..9 -> group 1 (uniform per lane).
// 8 rows/wave: each W-load instruction (the round-3 bottleneck: VMEM-issue bound) feeds 80 FMAs.
__global__ __launch_bounds__(512, 2)
void gumbel_vq_main(const float* __restrict__ hidden,
                    const int*   __restrict__ mask,
                    const float* __restrict__ gumbel,
                    const float* __restrict__ W,
                    const float* __restrict__ bias,
                    const float* __restrict__ codevec,
                    float* __restrict__ out,
                    float* __restrict__ ws)
{
    __shared__ float smem[5120];          // h-tile: 64*68=4352 floats; reused as [8][640] reduce buf
    const int tid  = threadIdx.x;
    const int tn   = tid & 63;
    const int tm   = tid >> 6;            // wave id 0..7
    const int row0 = blockIdx.x * M_TILE;

    // accumulators init = bias
    float acc[8][10];
    #pragma unroll
    for (int j = 0; j < 10; ++j) {
        float b = bias[tn + 64 * j];
        #pragma unroll
        for (int r = 0; r < 8; ++r) acc[r][j] = b;
    }

    // hidden staging: 64 rows x 64 k = 4096 floats = 512 threads x 2 float4
    const int lrow = tid >> 3;            // 0..63
    const int lk   = (tid & 7) * 8;       // 0..56
    const float* hsrc = hidden + (size_t)(row0 + lrow) * H + lk;

    float4 nxt0 = *(const float4*)hsrc;          // prefetch tile 0
    float4 nxt1 = *(const float4*)(hsrc + 4);

    for (int kt = 0; kt < H; kt += K_TILE) {
        __syncthreads();
        *(float4*)&smem[lrow * 68 + lk]     = nxt0;  // stride 68: <=2-way bank aliasing (free)
        *(float4*)&smem[lrow * 68 + lk + 4] = nxt1;
        __syncthreads();
        if (kt + K_TILE < H) {                       // prefetch next tile during compute
            nxt0 = *(const float4*)(hsrc + kt + K_TILE);
            nxt1 = *(const float4*)(hsrc + kt + K_TILE + 4);
        }

        #pragma unroll 2
        for (int kk = 0; kk < K_TILE; kk += 4) {
            float4 hv[8];
            #pragma unroll
            for (int r = 0; r < 8; ++r)
                hv[r] = *(const float4*)&smem[(tm * 8 + r) * 68 + kk];   // wave-broadcast reads
            #pragma unroll
            for (int q = 0; q < 4; ++q) {
                const float* Wk = W + (size_t)(kt + kk + q) * GV + tn;
                float w[10];
                #pragma unroll
                for (int j = 0; j < 10; ++j) w[j] = Wk[64 * j];          // coalesced per j
                #pragma unroll
                for (int r = 0; r < 8; ++r) {
                    float h = (q == 0) ? hv[r].x : (q == 1) ? hv[r].y : (q == 2) ? hv[r].z : hv[r].w;
                    #pragma unroll
                    for (int j = 0; j < 10; ++j)
                        acc[r][j] = fmaf(h, w[j], acc[r][j]);
                }
            }
        }
    }

    // ---- epilogue: per-row argmax / softmax / gather ----
    float marg[10];
    #pragma unroll
    for (int j = 0; j < 10; ++j) marg[j] = 0.f;

    // MUST be unrolled: runtime-indexed acc[r][...] would force the whole
    // accumulator array to scratch for the entire kernel (rule #20) — that
    // was a 23 GB HBM-write storm and 12x slowdown in round 1.
    #pragma unroll
    for (int r = 0; r < 8; ++r) {
        const int rloc = tm * 8 + r;
        const int row  = row0 + rloc;
        const float mrow = (mask[row] != 0) ? 1.f : 0.f;

        float z[10];
        #pragma unroll
        for (int j = 0; j < 10; ++j)
            z[j] = acc[r][j] + gumbel[(size_t)row * GV + tn + 64 * j];

        // lane-local argmax (logits+gumbel) and max (plain logits) per group
        float zm0 = z[0]; int zi0 = tn;          float lm0 = acc[r][0];
        #pragma unroll
        for (int j = 1; j < 5; ++j) {
            int c = tn + 64 * j;
            if (z[j] > zm0) { zm0 = z[j]; zi0 = c; }
            lm0 = fmaxf(lm0, acc[r][j]);
        }
        float zm1 = z[5]; int zi1 = tn + 320;    float lm1 = acc[r][5];
        #pragma unroll
        for (int j = 6; j < 10; ++j) {
            int c = tn + 64 * j;
            if (z[j] > zm1) { zm1 = z[j]; zi1 = c; }
            lm1 = fmaxf(lm1, acc[r][j]);
        }

        // 64-lane butterfly: argmax with first-index tie-break (matches jnp.argmax), plus plain max
        #pragma unroll
        for (int d = 32; d >= 1; d >>= 1) {
            float oz; int oi;
            oz = __shfl_xor(zm0, d, 64); oi = __shfl_xor(zi0, d, 64);
            if (oz > zm0 || (oz == zm0 && oi < zi0)) { zm0 = oz; zi0 = oi; }
            oz = __shfl_xor(zm1, d, 64); oi = __shfl_xor(zi1, d, 64);
            if (oz > zm1 || (oz == zm1 && oi < zi1)) { zm1 = oz; zi1 = oi; }
            lm0 = fmaxf(lm0, __shfl_xor(lm0, d, 64));
            lm1 = fmaxf(lm1, __shfl_xor(lm1, d, 64));
        }

        // softmax(plain logits) per group -> masked marginal accumulation
        float p[10];
        float s0 = 0.f, s1 = 0.f;
        #pragma unroll
        for (int j = 0; j < 5; ++j)  { p[j] = __expf(acc[r][j] - lm0); s0 += p[j]; }
        #pragma unroll
        for (int j = 5; j < 10; ++j) { p[j] = __expf(acc[r][j] - lm1); s1 += p[j]; }
        #pragma unroll
        for (int d = 32; d >= 1; d >>= 1) {
            s0 += __shfl_xor(s0, d, 64);
            s1 += __shfl_xor(s1, d, 64);
        }
        float inv0 = mrow / s0, inv1 = mrow / s1;
        #pragma unroll
        for (int j = 0; j < 5; ++j)  marg[j] += p[j] * inv0;
        #pragma unroll
        for (int j = 5; j < 10; ++j) marg[j] += p[j] * inv1;

        // codevector gather-write: lanes 0..31 write group 0's 128 floats, lanes 32..63 group 1
        int g   = tn >> 5;
        int idx = g ? (zi1 - V) : zi0;
        const float4* src = (const float4*)(codevec + ((size_t)g * V + idx) * DG);
        float4 vv = src[tn & 31];
        ((float4*)(out + (size_t)row * (2 * DG) + g * DG))[tn & 31] = vv;
    }

    // ---- cross-wave marginal reduce -> global atomics ----
    __syncthreads();                       // protect smem reuse
    #pragma unroll
    for (int j = 0; j < 10; ++j) smem[tm * GV + tn + 64 * j] = marg[j];
    __syncthreads();
    for (int c = tid; c < GV; c += 512) {
        float s = 0.f;
        #pragma unroll
        for (int w = 0; w < 8; ++w) s += smem[w * GV + c];
        atomicAdd(&ws[c], s);
    }

    // mask count: wave 0 covers the block's 64 rows, one atomic per block
    if (tm == 0) {
        int mr = (mask[row0 + tn] != 0);
        unsigned long long b = __ballot(mr);
        if (tn == 0) atomicAdd(&ws[GV], (float)__popcll(b));
    }
}

__global__ void gumbel_vq_finalize(const float* __restrict__ ws, float* __restrict__ out)
{
    __shared__ float red[GV];
    int t = threadIdx.x;
    float cnt = ws[GV];
    float p = ws[t] / cnt;
    red[t] = p * logf(p + 1e-7f);
    __syncthreads();
    if (t == 0) {
        float e0 = 0.f, e1 = 0.f;
        for (int i = 0; i < V; ++i)  e0 += red[i];
        for (int i = V; i < GV; ++i) e1 += red[i];
        out[(size_t)N_ROWS * 2 * DG] = expf(-e0) + expf(-e1);
    }
}

extern "C" void kernel_launch(void* const* d_in, const int* in_sizes, int n_in,
                              void* d_out, int out_size, void* d_ws, size_t ws_size,
                              hipStream_t stream)
{
    const float* hidden  = (const float*)d_in[0];
    const int*   mask    = (const int*)  d_in[1];
    const float* gumbel  = (const float*)d_in[2];
    const float* W       = (const float*)d_in[3];
    const float* bias    = (const float*)d_in[4];
    const float* codevec = (const float*)d_in[5];
    float* out = (float*)d_out;
    float* ws  = (float*)d_ws;

    hipMemsetAsync(d_ws, 0, (GV + 1) * sizeof(float), stream);
    gumbel_vq_main<<<N_ROWS / M_TILE, 512, 0, stream>>>(hidden, mask, gumbel, W, bias, codevec, out, ws);
    gumbel_vq_finalize<<<1, GV, 0, stream>>>(ws, out);
}